// Round 7
// baseline (403.113 us; speedup 1.0000x reference)
//
#include <hip/hip_runtime.h>

// ZeroWeave: x[B,C,64,64] -> out[B,C,190,190], out[:,:,::3,::3]=x, rest 0.
// B=32, C=64, num_zeros=2 (s=3). out = 295.7 MB, x = 33.5 MB.
//
// ===== R7: DIAGNOSTIC ROUND =====
// R1-R6: five kernel variants all land at the same inferred ~128 us while
// every per-pipe model says ~55-60 us -- and our kernel has NEVER appeared
// in the top-5 counter rows (the ~190 us harness poison fills mask it).
// This round runs the compose store phase TWICE (idempotent: same addresses,
// same data; __syncthreads() between passes blocks dead-store elimination)
// so our kernel becomes the longest dispatch and we finally get its
// FETCH_SIZE / WRITE_SIZE / VALUBusy / Occupancy row.
// Outcomes:
//  (a) dur ~110-130 us -> true cost ~55-65 us -> already at write roofline,
//      the 330 us total is harness overhead.
//  (b) dur ~255 us, FETCH ~600 MB -> store-miss RFO real, nt ineffective.
//  (c) dur ~255 us, FETCH ~35 MB  -> store-issue limit in this kernel shape.
//
// Pattern: 6 output rows = 1140 floats = exactly 285 float4 (16B-aligned).
// Plane = 9025 float4 = 31 full groups + 190-float4 partial group.
// Exact magic divs (range-verified):
//   e/190 = (e*44151)>>23  exact for e < 102300 (used e < 1140)
//   n/3   = (n*171)>>9     exact for n < 512    (used n < 190)
//   q/285 = (q*58868)>>24  exact for q <= 9024

typedef float vfloat4 __attribute__((ext_vector_type(4)));

constexpr int PLANE_IN   = 64 * 64;          // 4096 floats = 16 KB
constexpr int PLANE_OUT4 = 190 * 190 / 4;    // 9025 float4
constexpr int GROUP4     = 285;              // float4 per 6-row group
constexpr int NPLANES    = 32 * 64;          // 2048
constexpr int BLOCK      = 256;
constexpr int FULL_ITERS = PLANE_OUT4 / BLOCK;              // 35
constexpr int TAIL       = PLANE_OUT4 - FULL_ITERS * BLOCK; // 65

__global__ __launch_bounds__(BLOCK) void ZeroWeave_89601607729830_kernel(
    const float* __restrict__ x, float* __restrict__ out) {
    __shared__ float    xs[PLANE_IN];
    __shared__ unsigned tab[GROUP4];

    const int bc = blockIdx.x;
    const int t  = threadIdx.x;

    // Stage x plane -> LDS (1024 x 16B, coalesced, nontemporal).
    {
        const vfloat4* xp = reinterpret_cast<const vfloat4*>(x + bc * PLANE_IN);
        vfloat4* xl = reinterpret_cast<vfloat4*>(xs);
#pragma unroll
        for (int k = 0; k < PLANE_IN / 4 / BLOCK; ++k)
            xl[k * BLOCK + t] = __builtin_nontemporal_load(xp + k * BLOCK + t);
    }

    // Build the 285-entry pattern table (once per block).
    for (int p = t; p < GROUP4; p += BLOCK) {
        unsigned packed = 0;
#pragma unroll
        for (int j = 0; j < 4; ++j) {
            unsigned e  = 4u * p + j;              // element within group, <1140
            unsigned h  = (e * 44151u) >> 23;      // e / 190 (pattern row 0..5)
            unsigned w  = e - h * 190u;
            unsigned h3 = (h * 171u) >> 9;         // h / 3 (0 or 1)
            unsigned hm = h - h3 * 3u;
            unsigned w3 = (w * 171u) >> 9;         // w / 3
            unsigned wm = w - w3 * 3u;
            unsigned src = ((hm | wm) == 0u) ? (h3 * 64u + w3) : 255u; // <128 or 255
            packed |= src << (8 * j);
        }
        tab[p] = packed;
    }
    __syncthreads();

    vfloat4* op = reinterpret_cast<vfloat4*>(out) + bc * PLANE_OUT4;

    auto emit = [&](int q) {
        unsigned g      = ((unsigned)q * 58868u) >> 24;  // q / 285
        unsigned p      = (unsigned)q - g * 285u;
        unsigned xbase  = g << 7;                        // group's 128-float x chunk
        unsigned packed = tab[p];
        vfloat4 v;
#pragma unroll
        for (int j = 0; j < 4; ++j) {
            unsigned b = (packed >> (8 * j)) & 255u;
            float val  = xs[(xbase + b) & (PLANE_IN - 1)]; // always in-bounds
            v[j] = (b != 255u) ? val : 0.0f;               // cndmask, no branch
        }
        __builtin_nontemporal_store(v, op + q);
    };

    // TWO identical store passes (diagnostic doubling; result unchanged).
    for (int pass = 0; pass < 2; ++pass) {
#pragma unroll 4
        for (int k = 0; k < FULL_ITERS; ++k)
            emit(k * BLOCK + t);
        if (t < TAIL)
            emit(FULL_ITERS * BLOCK + t);
        __syncthreads();   // ordering point: keeps pass-1 stores live (no DSE)
    }
}

extern "C" void kernel_launch(void* const* d_in, const int* in_sizes, int n_in,
                              void* d_out, int out_size, void* d_ws, size_t ws_size,
                              hipStream_t stream) {
    const float* x = (const float*)d_in[0];
    // d_in[1] is num_zeros (==2), baked into constants.
    float* out = (float*)d_out;

    ZeroWeave_89601607729830_kernel<<<NPLANES, BLOCK, 0, stream>>>(x, out);
}

// Round 8
// 372.197 us; speedup vs baseline: 1.0831x; 1.0831x over previous
//
#include <hip/hip_runtime.h>

// ZeroWeave: x[B,C,64,64] -> out[B,C,190,190], out[:,:,::3,::3]=x, rest 0.
// B=32, C=64, num_zeros=2 (s=3). out = 295.7 MB, x = 33.5 MB.
//
// R7 diagnostic result: doubling the store phase cost only +73 us and the
// doubled kernel still ran under the ~185 us harness fills => single-pass
// kernel ~80 us (earlier ~128 us attribution was wrong; ~50 us of the bench
// total is other harness dispatches). Marginal store rate 295.7MB/73us =
// 4.05 TB/s vs 6.3 TB/s for the rocclr fill on the same dwordx4 pattern.
// Difference: our stores each waited on LDS-read+cndmask chains; fill data
// is a constant register.
//
// R8: split by data dependency. NO LDS, NO syncthreads, NO table.
//  Phase C (compose rows, h=3r): 64 rows x 95 float2 per plane. Per float2
//    {w0=2j, w0+1}: jm=j%3: jm==0 -> (x[2a],0); jm==1 -> (0,x[2a+1]);
//    jm==2 -> (0,0), a=j/3. One direct global x gather (consecutive lanes
//    read a ~170B window -> L1-coalesced; every x element is read exactly
//    once so LDS staging had zero reuse value) + 2 cndmask + 1 float2 store.
//  Phase Z (zero rows): rows 3k+1,3k+2 are a contiguous 1520B span ->
//    63 spans x 190 float2 per plane of PURE constant stores (fill-shaped:
//    store + addr-add, no data dependency).
//
// Magic divisions (exactness: m=ceil(2^s/d)=(2^s+e)/d, exact while n*e<2^s):
//   n/95  = (n*5519)>>19   e=17, exact for n < 30840   (used n < 6080)
//   n/190 = (n*5519)>>20   e=34, exact for n < 30840   (used n < 11970)
//   n/3   = (n*171)>>9     exact for n < 512           (used n < 95)

constexpr int PLANE_IN  = 64 * 64;       // 4096 floats
constexpr int PLANE_F2  = 190 * 190 / 2; // 18050 float2 per plane
constexpr int NPLANES   = 32 * 64;       // 2048
constexpr int BLOCK     = 256;

constexpr int NC = 64 * 95;              // 6080 compose float2 per plane
constexpr int C_FULL = NC / BLOCK;       // 23
constexpr int C_TAIL = NC - C_FULL * BLOCK;   // 192

constexpr int NZ = 63 * 190;             // 11970 zero float2 per plane
constexpr int Z_FULL = NZ / BLOCK;       // 46
constexpr int Z_TAIL = NZ - Z_FULL * BLOCK;   // 194

__global__ __launch_bounds__(BLOCK) void ZeroWeave_89601607729830_kernel(
    const float* __restrict__ x, float* __restrict__ out) {
    const int bc = blockIdx.x;
    const int t  = threadIdx.x;

    const float* xp = x + bc * PLANE_IN;
    float2* o2 = reinterpret_cast<float2*>(out) + bc * PLANE_F2;

    // ---- Phase C: compose rows (h = 3r), direct global x gather ----
    auto compose = [&](int idx) {            // idx in [0, 6080)
        unsigned u  = (unsigned)idx;
        unsigned r  = (u * 5519u) >> 19;     // idx / 95
        unsigned j  = u - r * 95u;           // float2 within row
        unsigned a  = (j * 171u) >> 9;       // j / 3
        unsigned jm = j - a * 3u;            // j % 3
        unsigned w3 = 2u * a + (jm == 1u);   // x column (<64, all jm)
        float val = xp[(r << 6) + w3];       // unconditional, in-bounds
        float2 v;
        v.x = (jm == 0u) ? val : 0.0f;
        v.y = (jm == 1u) ? val : 0.0f;
        o2[285u * r + j] = v;                // float2 slot of (row 3r, w0=2j)
    };
#pragma unroll 4
    for (int k = 0; k < C_FULL; ++k)
        compose(k * BLOCK + t);
    if (t < C_TAIL)
        compose(C_FULL * BLOCK + t);

    // ---- Phase Z: zero rows (3k+1, 3k+2) = contiguous 1520B spans ----
    const float2 z2 = make_float2(0.0f, 0.0f);
    auto zero = [&](int idx) {               // idx in [0, 11970)
        unsigned u = (unsigned)idx;
        unsigned s = (u * 5519u) >> 20;      // idx / 190 (span id)
        unsigned j = u - s * 190u;           // float2 within span
        o2[285u * s + 95u + j] = z2;         // span base = row 3s+1
    };
#pragma unroll 8
    for (int k = 0; k < Z_FULL; ++k)
        zero(k * BLOCK + t);
    if (t < Z_TAIL)
        zero(Z_FULL * BLOCK + t);
}

extern "C" void kernel_launch(void* const* d_in, const int* in_sizes, int n_in,
                              void* d_out, int out_size, void* d_ws, size_t ws_size,
                              hipStream_t stream) {
    const float* x = (const float*)d_in[0];
    // d_in[1] is num_zeros (==2), baked into constants.
    float* out = (float*)d_out;

    ZeroWeave_89601607729830_kernel<<<NPLANES, BLOCK, 0, stream>>>(x, out);
}

// Round 9
// 331.061 us; speedup vs baseline: 1.2176x; 1.1243x over previous
//
#include <hip/hip_runtime.h>

// ZeroWeave: x[B,C,64,64] -> out[B,C,190,190], out[:,:,::3,::3]=x, rest 0.
// B=32, C=64, num_zeros=2 (s=3). out = 295.7 MB, x = 33.5 MB.
// Floor at fill-demonstrated 6.3 TB/s: ~52 us. Measured kernel: ~80 us.
//
// Evidence so far: five structural variants (per-element decode, float2,
// plane-block LDS, branchless table, dependency-split fill-style) are all
// identical (~80 us, fill-normalized); R7 doubling put marginal pure-store
// rate at 4.05 TB/s vs 6.3 for rocclr fill; nt stores neutral (no RFO).
// => limiter is below the CU: too many concurrent write streams. R6 ran
// 2048 blocks = 2048 interleaved 144 KB streams (~16/HBM channel) => DRAM
// row-buffer thrash. rocclr fill: ~10% occupancy, ~1.5 MB contiguous per
// wave, few streams/channel, 6.3 TB/s.
//
// R9: same emit, but 512 blocks x 4 consecutive planes (2 blocks/CU,
// 577,600 B contiguous span per block, 4x fewer streams). Double-buffered
// LDS + VGPR prefetch of next plane; one barrier per plane (co-resident
// block covers the bubble).
//
// Pattern: 6 rows = 285 float4 exactly (16B-aligned groups); plane = 9025
// float4 = 31 groups + 190 partial (reuses table entries 0..189).
// Magic divs (range-proven): e/190=(e*44151)>>23 (e<102300);
// n/3=(n*171)>>9 (n<512); q/285=(q*58868)>>24 (q<=9024).

typedef float vfloat4 __attribute__((ext_vector_type(4)));

constexpr int PLANE_IN   = 64 * 64;          // 4096 floats = 16 KB
constexpr int PLANE_OUT4 = 190 * 190 / 4;    // 9025 float4
constexpr int GROUP4     = 285;
constexpr int BLOCK      = 256;
constexpr int PPB        = 4;                // planes per block
constexpr int GRID       = (32 * 64) / PPB;  // 512
constexpr int FULL_ITERS = PLANE_OUT4 / BLOCK;              // 35
constexpr int TAIL       = PLANE_OUT4 - FULL_ITERS * BLOCK; // 65
constexpr int STAGE_VEC  = PLANE_IN / 4 / BLOCK;            // 4 float4/thread

__global__ __launch_bounds__(BLOCK) void ZeroWeave_89601607729830_kernel(
    const float* __restrict__ x, float* __restrict__ out) {
    __shared__ float    xs[2][PLANE_IN];     // 32 KB double buffer
    __shared__ unsigned tab[GROUP4];

    const int t   = threadIdx.x;
    const int bc0 = blockIdx.x * PPB;

    // Build the 285-entry pattern table (once per block).
    for (int p = t; p < GROUP4; p += BLOCK) {
        unsigned packed = 0;
#pragma unroll
        for (int j = 0; j < 4; ++j) {
            unsigned e  = 4u * p + j;
            unsigned h  = (e * 44151u) >> 23;      // e / 190
            unsigned w  = e - h * 190u;
            unsigned h3 = (h * 171u) >> 9;         // h / 3
            unsigned hm = h - h3 * 3u;
            unsigned w3 = (w * 171u) >> 9;         // w / 3
            unsigned wm = w - w3 * 3u;
            unsigned src = ((hm | wm) == 0u) ? (h3 * 64u + w3) : 255u;
            packed |= src << (8 * j);
        }
        tab[p] = packed;
    }

    // Stage plane 0 into xs[0].
    {
        const vfloat4* xp = reinterpret_cast<const vfloat4*>(x + bc0 * PLANE_IN);
        vfloat4* xl = reinterpret_cast<vfloat4*>(xs[0]);
#pragma unroll
        for (int k = 0; k < STAGE_VEC; ++k)
            xl[k * BLOCK + t] = __builtin_nontemporal_load(xp + k * BLOCK + t);
    }
    __syncthreads();

    for (int p = 0; p < PPB; ++p) {
        // Prefetch next plane into VGPRs (overlaps with this plane's stores).
        vfloat4 pf[STAGE_VEC];
        if (p + 1 < PPB) {
            const vfloat4* xp =
                reinterpret_cast<const vfloat4*>(x + (bc0 + p + 1) * PLANE_IN);
#pragma unroll
            for (int k = 0; k < STAGE_VEC; ++k)
                pf[k] = __builtin_nontemporal_load(xp + k * BLOCK + t);
        }

        const float* xsp = xs[p & 1];
        vfloat4* op = reinterpret_cast<vfloat4*>(out) + (bc0 + p) * PLANE_OUT4;

        auto emit = [&](int q) {
            unsigned g      = ((unsigned)q * 58868u) >> 24;  // q / 285
            unsigned pp     = (unsigned)q - g * 285u;
            unsigned xbase  = g << 7;
            unsigned packed = tab[pp];
            vfloat4 v;
#pragma unroll
            for (int j = 0; j < 4; ++j) {
                unsigned b = (packed >> (8 * j)) & 255u;
                float val  = xsp[(xbase + b) & (PLANE_IN - 1)];
                v[j] = (b != 255u) ? val : 0.0f;
            }
            __builtin_nontemporal_store(v, op + q);
        };

#pragma unroll 4
        for (int k = 0; k < FULL_ITERS; ++k)
            emit(k * BLOCK + t);
        if (t < TAIL)
            emit(FULL_ITERS * BLOCK + t);

        // Commit prefetched plane to the other LDS buffer.
        if (p + 1 < PPB) {
            vfloat4* xl = reinterpret_cast<vfloat4*>(xs[(p + 1) & 1]);
#pragma unroll
            for (int k = 0; k < STAGE_VEC; ++k)
                xl[k * BLOCK + t] = pf[k];
            __syncthreads();
        }
    }
}

extern "C" void kernel_launch(void* const* d_in, const int* in_sizes, int n_in,
                              void* d_out, int out_size, void* d_ws, size_t ws_size,
                              hipStream_t stream) {
    const float* x = (const float*)d_in[0];
    // d_in[1] is num_zeros (==2), baked into constants.
    float* out = (float*)d_out;

    ZeroWeave_89601607729830_kernel<<<GRID, BLOCK, 0, stream>>>(x, out);
}